// Round 8
// baseline (36452.808 us; speedup 1.0000x reference)
//
#include <hip/hip_runtime.h>
#include <stdint.h>

namespace {

constexpr int H = 512, V = 64, B = 8, T = 48, D1 = 49, NDEC = 45, NSTEP = 102;
constexpr int NBLK = 256, TPB = 512;
constexpr int NG = 8, GMEM = NBLK / NG;

// pub layout: [par][j][b][p2] flat = par*16384 + j*32 + b*4 + p2  (floats)
constexpr size_t OFF_PUB = 0;
constexpr size_t OFF_IDX = 2 * 16384;               // ints from here
constexpr size_t OFF_BAR = OFF_IDX + NSTEP * B;     // 512 ints

// relaxed agent-scope (sc1) accessors: coherent at L3, no fences, no L2 flush
__device__ __forceinline__ float ldA(const float* p) {
  return __hip_atomic_load(p, __ATOMIC_RELAXED, __HIP_MEMORY_SCOPE_AGENT);
}
__device__ __forceinline__ void stA(float* p, float v) {
  __hip_atomic_store(p, v, __ATOMIC_RELAXED, __HIP_MEMORY_SCOPE_AGENT);
}
__device__ __forceinline__ int ldAi(const int* p) {
  return __hip_atomic_load(p, __ATOMIC_RELAXED, __HIP_MEMORY_SCOPE_AGENT);
}
__device__ __forceinline__ void stAi(int* p, int v) {
  __hip_atomic_store(p, v, __ATOMIC_RELAXED, __HIP_MEMORY_SCOPE_AGENT);
}

__device__ __forceinline__ void tf2x32(uint32_t k0, uint32_t k1,
                                       uint32_t& x0, uint32_t& x1) {
  const uint32_t ks2 = k0 ^ k1 ^ 0x1BD11BDAu;
  x0 += k0; x1 += k1;
#define RR(r) { x0 += x1; x1 = (x1 << (r)) | (x1 >> (32-(r))); x1 ^= x0; }
  RR(13) RR(15) RR(26) RR(6)  x0 += k1;  x1 += ks2 + 1u;
  RR(17) RR(29) RR(16) RR(24) x0 += ks2; x1 += k0 + 2u;
  RR(13) RR(15) RR(26) RR(6)  x0 += k0;  x1 += k1 + 3u;
  RR(17) RR(29) RR(16) RR(24) x0 += k1;  x1 += ks2 + 4u;
  RR(13) RR(15) RR(26) RR(6)  x0 += ks2; x1 += k0 + 5u;
#undef RR
}

__device__ __forceinline__ float gumbel_from_bits(uint32_t bits) {
  float u = __uint_as_float((bits >> 9) | 0x3F800000u) - 1.0f;
  u = u + 1e-9f;
  return -logf(-logf(u));
}

__global__ __launch_bounds__(512) void k_zero(float* __restrict__ ws) {
  int* bar = (int*)ws + OFF_BAR;
  if (threadIdx.x < 512) stAi(&bar[threadIdx.x], 0);
  for (int i = threadIdx.x; i < 16384; i += 512) stA(&ws[i], 0.0f);
}

// fence-free two-level grid barrier (r6/r7-proven):
// sc1 data + vmcnt drain before arrive => visibility without cache flushes
__device__ __forceinline__ void gbar(int* bar, int grp, int ep) {
  asm volatile("s_waitcnt vmcnt(0)" ::: "memory");
  __syncthreads();
  if (threadIdx.x == 0) {
    int old = __hip_atomic_fetch_add(&bar[16 + 16 * grp], 1,
                                     __ATOMIC_RELAXED, __HIP_MEMORY_SCOPE_AGENT);
    if (((old + 1) & (GMEM - 1)) == 0) {
      int oldG = __hip_atomic_fetch_add(&bar[0], 1,
                                        __ATOMIC_RELAXED, __HIP_MEMORY_SCOPE_AGENT);
      if (((oldG + 1) & (NG - 1)) == 0) {
        #pragma unroll
        for (int q = 0; q < NG; ++q) stAi(&bar[160 + 16 * q], ep);
      }
    }
    int guard = 0;
    while (ldAi(&bar[160 + 16 * grp]) < ep) {
      __builtin_amdgcn_s_sleep(2);
      if (++guard > (1 << 20)) break;   // fail-visible, never hangs
    }
  }
  __syncthreads();
}

__global__ __launch_bounds__(TPB, 2) void k_main(
    const float* __restrict__ x,  const float* __restrict__ wa,
    const float* __restrict__ ba, const float* __restrict__ lat,
    const float* __restrict__ tau,const float* __restrict__ we,
    const float* __restrict__ be, float* __restrict__ ws,
    float* __restrict__ out) {
  const int blk = blockIdx.x, tid = threadIdx.x;
  const int w = tid >> 6, lane = tid & 63;
  const int p = blk >> 6, g = blk & 63, grp = blk & 7;
  float* pub = ws + OFF_PUB;
  int* idxA = (int*)ws + OFF_IDX;
  int* bar  = (int*)ws + OFF_BAR;

  __shared__ float s_pub[128 * 35 + 8];  // staged pub chunk, stride-35 pad
  __shared__ float s_h[8 * 128];         // h[b][il]
  __shared__ float s_buf[8 * 8 * 49];    // delay partials, block-local (12.5 KB)
  __shared__ float s_hdl[512];           // leader: full h_del
  __shared__ float s_red[256];           // leader: y partials
  __shared__ int   s_ptr[8], s_cidx[8], s_done8[8];

  // ---------------- init ----------------
  for (int q2 = tid; q2 < 8 * 8 * 49; q2 += TPB) s_buf[q2] = 0.0f;
  if (tid < 8) { s_ptr[tid] = 0; s_cidx[tid] = 0; s_done8[tid] = 0; }

  // STEP-INVARIANT credit*lat slice in VGPRs: q[i] for (ho=g*8+w, d=lane)
  // identical op sequence to the r3-verified credit: clip, sub, mul, abs,
  // sub, max, then * lat  -> bit-equal contributions.
  float q[128];
  {
    const int ho = g * 8 + w;
    const float dd = (float)lane;
    const float inv = 1.0f / 24.0f, inv2 = inv * inv;
    const float* taur = tau + (size_t)ho * H + p * 128;
    const float* latr = lat + (size_t)ho * H + p * 128;
    #pragma unroll
    for (int i = 0; i < 128; ++i) {
      float tc = fminf(fmaxf(taur[i], 1.0f), 48.0f);
      float cr = fmaxf(0.0f, inv - fabsf((dd - tc) * inv2));
      q[i] = cr * latr[i];
    }
  }

  uint32_t ka = 0u, kb = (uint32_t)blk;
  if (blk < B) tf2x32(0u, 42u, ka, kb);     // leader sample key

  gbar(bar, grp, 1);

  // ---------------- 102 sequential steps ----------------
  for (int t = 0; t < NSTEP; ++t) {
    const bool thinkM = (t >= T && t < T + 9);
    const bool decM   = (t >= T + 9);

    // 1. replicated control-state update (thread b handles sample b)
    if (tid < 8 && t >= 1) {
      const int b = tid;
      const bool prevThink = (t - 1 >= T) && (t - 1 < T + 9);
      const bool aP = prevThink ? (s_done8[b] == 0) : true;
      if (t - 1 >= T) {
        int ix = ldAi(&idxA[(t - 1) * 8 + b]);
        if (aP) s_cidx[b] = ix;
        if (prevThink && (ix == 63 || (t - 1 - T) == 8)) s_done8[b] = 1;
      }
      if (aP) { int pv = s_ptr[b]; s_ptr[b] = (pv + 1 == D1) ? 0 : pv + 1; }
    }
    __syncthreads();

    int actM = 0;
    #pragma unroll
    for (int b = 0; b < B; ++b)
      actM |= ((thinkM ? (s_done8[b] ^ 1) : 1) & 1) << b;

    // 2. stage pub chunk (coalesced); leaders stage full h_del (strided)
    {
      const float* pubR = pub + ((size_t)(t & 1) * 16384 + p * 4096);
      #pragma unroll
      for (int k = 0; k < 8; ++k) {
        int f = k * 512 + tid;
        float v = ldA(&pubR[f]);
        s_pub[(f >> 5) * 35 + (f & 31)] = v;
      }
    }
    if (blk < B && t >= T) {
      const float* pr = pub + ((size_t)(t & 1) * 16384 + tid * 32 + blk * 4);
      float h0 = ldA(pr), h1 = ldA(pr + 1), h2 = ldA(pr + 2), h3 = ldA(pr + 3);
      s_hdl[tid] = ((h0 + h1) + h2) + h3;
    }
    __syncthreads();

    // 3. h for this block's chunk; leaders also y partials
    #pragma unroll
    for (int it2 = 0; it2 < 2; ++it2) {
      int q2 = tid + it2 * TPB;
      int b = q2 >> 7, il = q2 & 127;
      int j = p * 128 + il;
      int sp = il * 35 + b * 4;
      float h0 = s_pub[sp], h1 = s_pub[sp + 1], h2 = s_pub[sp + 2], h3 = s_pub[sp + 3];
      float hd = ((h0 + h1) + h2) + h3;
      float acc;
      if (t <= T) {      // encoder rows; first think step uses x[:,T-1,:]
        const float* xr = x + ((size_t)b * T + (t < T ? t : T - 1)) * V;
        const float* war = wa + (size_t)j * V;
        acc = ba[j] + hd;
        #pragma unroll
        for (int v = 0; v < V; v += 4) {
          float4 w4 = *(const float4*)(war + v);
          float4 x4 = *(const float4*)(xr + v);
          acc = fmaf(w4.x, x4.x, acc); acc = fmaf(w4.y, x4.y, acc);
          acc = fmaf(w4.z, x4.z, acc); acc = fmaf(w4.w, x4.w, acc);
        }
      } else {           // cur is exactly one-hot -> single add (bit-equal)
        acc = (ba[j] + hd) + wa[(size_t)j * V + s_cidx[b]];
      }
      s_h[b * 128 + il] = tanhf(acc);
    }
    if (blk < B && t >= T && tid < 256) {
      int o = tid >> 2, q2 = tid & 3;
      const float* wer = we + (size_t)o * H + q2 * 128;
      const float* hp  = &s_hdl[q2 * 128];
      float a2 = 0.0f;
      for (int i2 = 0; i2 < 128; i2 += 4) {
        float4 w4 = *(const float4*)(wer + i2);
        a2 = fmaf(w4.x, hp[i2],     a2); a2 = fmaf(w4.y, hp[i2 + 1], a2);
        a2 = fmaf(w4.z, hp[i2 + 2], a2); a2 = fmaf(w4.w, hp[i2 + 3], a2);
      }
      s_red[tid] = a2;
    }
    __syncthreads();

    // 4. leaders finalize y/gumbel/idx; everyone scatters into LDS s_buf
    if (blk < B && t >= T && tid < V) {
      const int o = tid, it = t - T;
      float y = ((s_red[o*4] + s_red[o*4+1]) + (s_red[o*4+2] + s_red[o*4+3])) + be[o];
      if (decM && o < V - 1)
        out[((size_t)blk * NDEC + (t - T - 9)) * (V - 1) + o] = y;
      uint32_t data = (it < 9) ? (uint32_t)it : (uint32_t)(10000 + (it - 9));
      uint32_t e = 0u, f = data; tf2x32(ka, kb, e, f);
      uint32_t r0 = 0u, r1 = (uint32_t)o; tf2x32(e, f, r0, r1);
      float bv = y + gumbel_from_bits(r0 ^ r1);
      int bi = o;
      #pragma unroll
      for (int m = 32; m >= 1; m >>= 1) {
        float ov = __shfl_xor(bv, m, 64);
        int   oi = __shfl_xor(bi, m, 64);
        if (ov > bv || (ov == bv && oi < bi)) { bv = ov; bi = oi; }
      }
      if (o == 0) stAi(&idxA[t * 8 + blk], bi);
    }
    {
      float acc[B];
      #pragma unroll
      for (int b = 0; b < B; ++b) acc[b] = 0.0f;
      #pragma unroll
      for (int ii = 0; ii < 128; ii += 4) {
        float4 h4[B];
        #pragma unroll
        for (int b = 0; b < B; ++b) h4[b] = *(const float4*)(&s_h[b * 128 + ii]);
        #pragma unroll
        for (int k = 0; k < 4; ++k) {
          const float qv = q[ii + k];
          #pragma unroll
          for (int b = 0; b < B; ++b)
            acc[b] = fmaf(qv, ((const float*)&h4[b])[k], acc[b]);
        }
      }
      if (lane >= 1 && lane <= 48) {
        #pragma unroll
        for (int b = 0; b < B; ++b) {
          if ((actM >> b) & 1) {
            int slot = s_ptr[b] + lane; if (slot >= D1) slot -= D1;
            int a = (b * 8 + w) * 49 + slot;
            // d=48 is the FIRST write to a freshly-consumed slot: overwrite
            // implements the reference's slot-clear (deferred, r5-r7 proven).
            float old = s_buf[a];
            s_buf[a] = (lane == 48) ? acc[b] : (old + acc[b]);
          }
        }
      }
    }
    __syncthreads();

    // 5. publish next step's h_del partials (ptr_{t+1} known NOW)
    if (tid < 64) {
      int hl = tid >> 3, b = tid & 7;
      int sn = ((actM >> b) & 1) ? s_ptr[b] + 1 : s_ptr[b];
      if (sn >= D1) sn -= D1;
      float val = s_buf[(b * 8 + hl) * 49 + sn];
      stA(&pub[(size_t)((t + 1) & 1) * 16384 + (g * 8 + hl) * 32 + b * 4 + p], val);
    }

    gbar(bar, grp, t + 2);
  }
}

} // anonymous namespace

extern "C" void kernel_launch(void* const* d_in, const int* in_sizes, int n_in,
                              void* d_out, int out_size, void* d_ws, size_t ws_size,
                              hipStream_t stream) {
  (void)in_sizes; (void)n_in; (void)out_size; (void)ws_size;
  const float* x   = (const float*)d_in[0];
  const float* wa  = (const float*)d_in[1];
  const float* ba  = (const float*)d_in[2];
  const float* lat = (const float*)d_in[3];
  const float* tau = (const float*)d_in[4];
  const float* we  = (const float*)d_in[5];
  const float* be  = (const float*)d_in[6];
  float* out = (float*)d_out;
  float* ws  = (float*)d_ws;

  k_zero<<<dim3(1), dim3(512), 0, stream>>>(ws);
  k_main<<<dim3(NBLK), dim3(TPB), 0, stream>>>(x, wa, ba, lat, tau, we, be, ws, out);
}

// Round 9
// 1552.307 us; speedup vs baseline: 23.4830x; 23.4830x over previous
//
#include <hip/hip_runtime.h>
#include <stdint.h>

namespace {

constexpr int H = 512, V = 64, B = 8, T = 48, D1 = 49, NDEC = 45, NSTEP = 102;
constexpr int NSC  = 256;          // scatter blocks: 8 p-chunks x 32 g-groups
constexpr int NBLK = NSC + 8;      // + 8 dedicated y-blocks
constexpr int TPB  = 512;
constexpr int NG = 8, GMEM = NBLK / NG;   // 33 per group

// pub layout: [par][j<512][b<8][p<8]  flat = par*32768 + j*64 + b*8 + p
constexpr size_t OFF_PUB = 0;
constexpr size_t OFF_IDX = 2 * 32768;            // ints from here
constexpr size_t OFF_BAR = OFF_IDX + NSTEP * B;  // 512 ints

// relaxed agent-scope (sc1) accessors: L3-coherent, no fences, no L2 flush
__device__ __forceinline__ float ldA(const float* p) {
  return __hip_atomic_load(p, __ATOMIC_RELAXED, __HIP_MEMORY_SCOPE_AGENT);
}
__device__ __forceinline__ void stA(float* p, float v) {
  __hip_atomic_store(p, v, __ATOMIC_RELAXED, __HIP_MEMORY_SCOPE_AGENT);
}
__device__ __forceinline__ int ldAi(const int* p) {
  return __hip_atomic_load(p, __ATOMIC_RELAXED, __HIP_MEMORY_SCOPE_AGENT);
}
__device__ __forceinline__ void stAi(int* p, int v) {
  __hip_atomic_store(p, v, __ATOMIC_RELAXED, __HIP_MEMORY_SCOPE_AGENT);
}

__device__ __forceinline__ void tf2x32(uint32_t k0, uint32_t k1,
                                       uint32_t& x0, uint32_t& x1) {
  const uint32_t ks2 = k0 ^ k1 ^ 0x1BD11BDAu;
  x0 += k0; x1 += k1;
#define RR(r) { x0 += x1; x1 = (x1 << (r)) | (x1 >> (32-(r))); x1 ^= x0; }
  RR(13) RR(15) RR(26) RR(6)  x0 += k1;  x1 += ks2 + 1u;
  RR(17) RR(29) RR(16) RR(24) x0 += ks2; x1 += k0 + 2u;
  RR(13) RR(15) RR(26) RR(6)  x0 += k0;  x1 += k1 + 3u;
  RR(17) RR(29) RR(16) RR(24) x0 += k1;  x1 += ks2 + 4u;
  RR(13) RR(15) RR(26) RR(6)  x0 += ks2; x1 += k0 + 5u;
#undef RR
}

__device__ __forceinline__ float gumbel_from_bits(uint32_t bits) {
  float u = __uint_as_float((bits >> 9) | 0x3F800000u) - 1.0f;
  u = u + 1e-9f;
  return -logf(-logf(u));
}

__global__ __launch_bounds__(512) void k_zero(float* __restrict__ ws) {
  int* bar = (int*)ws + OFF_BAR;
  if (threadIdx.x < 512) stAi(&bar[threadIdx.x], 0);
  for (int i = threadIdx.x; i < 32768; i += 512) stA(&ws[i], 0.0f);  // pub par0
}

// fence-free two-level grid barrier (r6/r7-proven):
// sc1 data + vmcnt drain before arrive => visibility without cache flushes
__device__ __forceinline__ void gbar(int* bar, int grp, int ep) {
  asm volatile("s_waitcnt vmcnt(0)" ::: "memory");
  __syncthreads();
  if (threadIdx.x == 0) {
    int old = __hip_atomic_fetch_add(&bar[16 + 16 * grp], 1,
                                     __ATOMIC_RELAXED, __HIP_MEMORY_SCOPE_AGENT);
    if (((old + 1) % GMEM) == 0) {
      int oldG = __hip_atomic_fetch_add(&bar[0], 1,
                                        __ATOMIC_RELAXED, __HIP_MEMORY_SCOPE_AGENT);
      if (((oldG + 1) & (NG - 1)) == 0) {
        #pragma unroll
        for (int q = 0; q < NG; ++q) stAi(&bar[160 + 16 * q], ep);
      }
    }
    int guard = 0;
    while (ldAi(&bar[160 + 16 * grp]) < ep) {
      __builtin_amdgcn_s_sleep(2);
      if (++guard > (1 << 20)) break;   // fail-visible, never hangs
    }
  }
  __syncthreads();
}

__global__ __launch_bounds__(TPB, 4) void k_main(
    const float* __restrict__ x,  const float* __restrict__ wa,
    const float* __restrict__ ba, const float* __restrict__ lat,
    const float* __restrict__ tau,const float* __restrict__ we,
    const float* __restrict__ be, float* __restrict__ ws,
    float* __restrict__ out) {
  const int blk = blockIdx.x, tid = threadIdx.x;
  const int grp = blk % NG;
  float* pub = ws + OFF_PUB;
  int* idxA = (int*)ws + OFF_IDX;
  int* bar  = (int*)ws + OFF_BAR;

  const bool isY = (blk >= NSC);
  const int p  = blk >> 5;          // 0..7 (64-i chunk)      [scatter blocks]
  const int g  = blk & 31;          // 0..31 (16-ho group)
  const int w  = tid >> 6, lane = tid & 63;
  const int cb = p * 64;            // chunk base in i/j space
  const int yb = blk - NSC;         // sample for y-blocks

  __shared__ float s_pub[64 * 65 + 8];  // staged chunk partials, stride-65 pad
  __shared__ float s_h[8 * 64];         // h[b][il]
  __shared__ float s_tc[16 * 64];       // pre-clipped tau for 16 ho x 64 i
  __shared__ float s_lat[16 * 64];
  __shared__ float s_buf[8 * 16 * 49];  // delay partials [b*16+hl][49] (24.5KB)
  __shared__ float s_hdl[512];          // y-block: full h_del
  __shared__ float s_red[256];          // y-block: y partials
  __shared__ int   s_ptr[8], s_cidx[8], s_done8[8];

  // ---------------- init ----------------
  if (!isY) {
    for (int q2 = tid; q2 < 8 * 16 * 49; q2 += TPB) s_buf[q2] = 0.0f;
    for (int q2 = tid; q2 < 16 * 64; q2 += TPB) {
      int hl = q2 >> 6, ii = q2 & 63;
      int ho = g * 16 + hl, i = cb + ii;
      float tv = tau[(size_t)ho * H + i];
      s_tc[q2]  = fminf(fmaxf(tv, 1.0f), 48.0f);   // same clip ops as r7
      s_lat[q2] = lat[(size_t)ho * H + i];
    }
    if (tid < 8) { s_ptr[tid] = 0; s_cidx[tid] = 0; s_done8[tid] = 0; }
  }
  uint32_t ka = 0u, kb = (uint32_t)yb;
  if (isY) tf2x32(0u, 42u, ka, kb);     // sample key (partitionable split)

  gbar(bar, grp, 1);

  // ---------------- 102 sequential steps ----------------
  for (int t = 0; t < NSTEP; ++t) {
    const bool thinkM = (t >= T && t < T + 9);
    const bool decM   = (t >= T + 9);

    if (!isY) {
      // 1. replicated control-state update (thread b handles sample b)
      if (tid < 8 && t >= 1) {
        const int b = tid;
        const bool prevThink = (t - 1 >= T) && (t - 1 < T + 9);
        const bool aP = prevThink ? (s_done8[b] == 0) : true;
        if (t - 1 >= T) {
          int ix = ldAi(&idxA[(t - 1) * 8 + b]);
          if (aP) s_cidx[b] = ix;
          if (prevThink && (ix == 63 || (t - 1 - T) == 8)) s_done8[b] = 1;
        }
        if (aP) { int pv = s_ptr[b]; s_ptr[b] = (pv + 1 == D1) ? 0 : pv + 1; }
      }
      __syncthreads();

      int actM = 0;
      #pragma unroll
      for (int b = 0; b < B; ++b)
        actM |= ((thinkM ? (s_done8[b] ^ 1) : 1) & 1) << b;

      // 2. stage pub chunk (coalesced): 4096 floats = [il][b*8+p2]
      {
        const float* pubR = pub + ((size_t)(t & 1) * 32768 + (size_t)cb * 64);
        #pragma unroll
        for (int k = 0; k < 8; ++k) {
          int f = k * 512 + tid;
          float v = ldA(&pubR[f]);
          s_pub[(f >> 6) * 65 + (f & 63)] = v;
        }
      }
      __syncthreads();

      // 3. h for this block's chunk (1 per thread)
      {
        int il = tid & 63, b = tid >> 6;
        int j = cb + il;
        int sp = il * 65 + b * 8;
        // fixed 8-partial tree: ((0+1)+(2+3)) + ((4+5)+(6+7))
        float hd = ((s_pub[sp]   + s_pub[sp+1]) + (s_pub[sp+2] + s_pub[sp+3]))
                 + ((s_pub[sp+4] + s_pub[sp+5]) + (s_pub[sp+6] + s_pub[sp+7]));
        float acc;
        if (t <= T) {     // encoder rows; first think step uses x[:,T-1,:]
          const float* xr = x + ((size_t)b * T + (t < T ? t : T - 1)) * V;
          const float* war = wa + (size_t)j * V;
          acc = ba[j] + hd;
          #pragma unroll
          for (int v = 0; v < V; v += 4) {
            float4 w4 = *(const float4*)(war + v);
            float4 x4 = *(const float4*)(xr + v);
            acc = fmaf(w4.x, x4.x, acc); acc = fmaf(w4.y, x4.y, acc);
            acc = fmaf(w4.z, x4.z, acc); acc = fmaf(w4.w, x4.w, acc);
          }
        } else {          // cur is exactly one-hot -> single add (bit-equal)
          acc = (ba[j] + hd) + wa[(size_t)j * V + s_cidx[b]];
        }
        s_h[b * 64 + il] = tanhf(acc);
      }
      __syncthreads();

      // 4. scatter: wave w owns TWO rows (hoA=2w, hoB=2w+1), lane = delay d
      {
        const float dd = (float)lane;
        const float inv = 1.0f / 24.0f, inv2 = inv * inv;
        float accA[8], accB[8];
        #pragma unroll
        for (int b = 0; b < B; ++b) { accA[b] = 0.0f; accB[b] = 0.0f; }
        const float* tcA = &s_tc[(w * 2) * 64];
        const float* ltA = &s_lat[(w * 2) * 64];
        const float* tcB = &s_tc[(w * 2 + 1) * 64];
        const float* ltB = &s_lat[(w * 2 + 1) * 64];
        #pragma unroll 4
        for (int ii = 0; ii < 64; ii += 4) {
          float4 tA = *(const float4*)(tcA + ii);
          float4 lA = *(const float4*)(ltA + ii);
          float4 tB = *(const float4*)(tcB + ii);
          float4 lB = *(const float4*)(ltB + ii);
          float qA[4], qB[4];
          #pragma unroll
          for (int k = 0; k < 4; ++k) {
            // per-(ho,i) op sequence identical to r7: sub,mul,abs,rsub,max,mul
            float ta = ((const float*)&tA)[k];
            qA[k] = fmaxf(0.0f, inv - fabsf((dd - ta) * inv2)) * ((const float*)&lA)[k];
            float tb = ((const float*)&tB)[k];
            qB[k] = fmaxf(0.0f, inv - fabsf((dd - tb) * inv2)) * ((const float*)&lB)[k];
          }
          #pragma unroll
          for (int b = 0; b < B; ++b) {
            float4 h4 = *(const float4*)(&s_h[b * 64 + ii]);
            const float* hp = (const float*)&h4;
            #pragma unroll
            for (int k = 0; k < 4; ++k) accA[b] = fmaf(qA[k], hp[k], accA[b]);
            #pragma unroll
            for (int k = 0; k < 4; ++k) accB[b] = fmaf(qB[k], hp[k], accB[b]);
          }
        }
        if (lane >= 1 && lane <= 48) {
          #pragma unroll
          for (int b = 0; b < B; ++b) {
            if ((actM >> b) & 1) {
              int slot = s_ptr[b] + lane; if (slot >= D1) slot -= D1;
              // d=48 is the FIRST write to the freshly-consumed slot:
              // overwrite implements the reference's slot-clear (deferred).
              int aA = (b * 16 + w * 2) * 49 + slot;
              float oA = s_buf[aA];
              s_buf[aA] = (lane == 48) ? accA[b] : (oA + accA[b]);
              int aB = (b * 16 + w * 2 + 1) * 49 + slot;
              float oB = s_buf[aB];
              s_buf[aB] = (lane == 48) ? accB[b] : (oB + accB[b]);
            }
          }
        }
      }
      __syncthreads();

      // 5. publish next step's h_del partials (ptr_{t+1} known NOW)
      if (tid < 128) {
        int hl = tid >> 3, b = tid & 7;
        int sn = ((actM >> b) & 1) ? s_ptr[b] + 1 : s_ptr[b];
        if (sn >= D1) sn -= D1;
        float val = s_buf[(b * 16 + hl) * 49 + sn];
        stA(&pub[(size_t)((t + 1) & 1) * 32768
                 + (size_t)(g * 16 + hl) * 64 + b * 8 + p], val);
      }
    } else {
      // ===== y-block for sample yb: runs concurrently with scatter =====
      if (t >= T) {
        {  // stage full h_del (same 8-partial tree as h-compute)
          const float* pr = pub + ((size_t)(t & 1) * 32768 + (size_t)tid * 64 + yb * 8);
          float p0 = ldA(pr),     p1 = ldA(pr + 1), p2 = ldA(pr + 2), p3 = ldA(pr + 3);
          float p4 = ldA(pr + 4), p5 = ldA(pr + 5), p6 = ldA(pr + 6), p7 = ldA(pr + 7);
          s_hdl[tid] = ((p0 + p1) + (p2 + p3)) + ((p4 + p5) + (p6 + p7));
        }
      }
      __syncthreads();
      if (t >= T && tid < 256) {   // y partials: identical chains to r7
        int o = tid >> 2, q2 = tid & 3;
        const float* wer = we + (size_t)o * H + q2 * 128;
        const float* hp  = &s_hdl[q2 * 128];
        float a2 = 0.0f;
        for (int i2 = 0; i2 < 128; i2 += 4) {
          float4 w4 = *(const float4*)(wer + i2);
          a2 = fmaf(w4.x, hp[i2],     a2); a2 = fmaf(w4.y, hp[i2 + 1], a2);
          a2 = fmaf(w4.z, hp[i2 + 2], a2); a2 = fmaf(w4.w, hp[i2 + 3], a2);
        }
        s_red[tid] = a2;
      }
      __syncthreads();
      if (t >= T && tid < V) {
        const int o = tid, it = t - T;
        float y = ((s_red[o*4] + s_red[o*4+1]) + (s_red[o*4+2] + s_red[o*4+3])) + be[o];
        if (decM && o < V - 1)
          out[((size_t)yb * NDEC + (t - T - 9)) * (V - 1) + o] = y;
        uint32_t data = (it < 9) ? (uint32_t)it : (uint32_t)(10000 + (it - 9));
        uint32_t e = 0u, f = data; tf2x32(ka, kb, e, f);
        uint32_t r0 = 0u, r1 = (uint32_t)o; tf2x32(e, f, r0, r1);
        float bv = y + gumbel_from_bits(r0 ^ r1);
        int bi = o;
        #pragma unroll
        for (int m = 32; m >= 1; m >>= 1) {
          float ov = __shfl_xor(bv, m, 64);
          int   oi = __shfl_xor(bi, m, 64);
          if (ov > bv || (ov == bv && oi < bi)) { bv = ov; bi = oi; }
        }
        if (o == 0) stAi(&idxA[t * 8 + yb], bi);
      }
    }

    gbar(bar, grp, t + 2);
  }
}

} // anonymous namespace

extern "C" void kernel_launch(void* const* d_in, const int* in_sizes, int n_in,
                              void* d_out, int out_size, void* d_ws, size_t ws_size,
                              hipStream_t stream) {
  (void)in_sizes; (void)n_in; (void)out_size; (void)ws_size;
  const float* x   = (const float*)d_in[0];
  const float* wa  = (const float*)d_in[1];
  const float* ba  = (const float*)d_in[2];
  const float* lat = (const float*)d_in[3];
  const float* tau = (const float*)d_in[4];
  const float* we  = (const float*)d_in[5];
  const float* be  = (const float*)d_in[6];
  float* out = (float*)d_out;
  float* ws  = (float*)d_ws;

  k_zero<<<dim3(1), dim3(512), 0, stream>>>(ws);
  k_main<<<dim3(NBLK), dim3(TPB), 0, stream>>>(x, wa, ba, lat, tau, we, be, ws, out);
}